// Round 10
// baseline (441.603 us; speedup 1.0000x reference)
//
#include <hip/hip_runtime.h>
#include <math.h>

namespace {

constexpr int N    = 32768;
constexpr int E    = 524288;
constexpr int ETOT = E + N;
constexpr int FIN  = 256;
constexpr int H    = 4;
constexpr int C    = 128;
constexpr int HC   = H * C;          // 512
constexpr float NEG    = 0.2f;
constexpr float BN_EPS = 1e-5f;

typedef __attribute__((ext_vector_type(8))) short    bf16x8;
typedef __attribute__((ext_vector_type(4))) float    f32x4;
typedef __attribute__((ext_vector_type(2))) unsigned u32x2;

__device__ __forceinline__ float lrelu(float x) { return x >= 0.f ? x : NEG * x; }

__device__ __forceinline__ unsigned short f2b(float f) {  // rnne f32->bf16
  unsigned u = __float_as_uint(f);
  u = (u + 0x7fffu + ((u >> 16) & 1u)) >> 16;
  return (unsigned short)u;
}
__device__ __forceinline__ unsigned pack2(float a, float b) {
  return (unsigned)f2b(a) | ((unsigned)f2b(b) << 16);
}
__device__ __forceinline__ float blo(unsigned u) { return __uint_as_float(u << 16); }
__device__ __forceinline__ float bhi(unsigned u) { return __uint_as_float(u & 0xffff0000u); }

// async global->LDS, 16B per lane; LDS dest = base + lane*16 (linear)
__device__ __forceinline__ void gll16(const unsigned short* g, unsigned short* l) {
  __builtin_amdgcn_global_load_lds(
      (const __attribute__((address_space(1))) unsigned int*)g,
      (__attribute__((address_space(3))) unsigned int*)l, 16, 0, 0);
}

// ---------------- k_prep: weight stacks + attvecs + zeroing, blockIdx-ranged --------
constexpr int PB_W1  = (C * 4 * FIN) / 256;   // 512
constexpr int PB_W2  = (C * 4 * C) / 256;     // 256
constexpr int PB_WF  = (C * C) / 256;         // 64
constexpr int PB_AV1 = (8 * FIN) / 256;       // 8
constexpr int PB_AV2 = (8 * C) / 256;         // 4
constexpr int PB_Z   = (2 * N + 512) / 256;   // 258
constexpr int PB_TOT = PB_W1 + PB_W2 + PB_WF + PB_AV1 + PB_AV2 + PB_Z;

__global__ __launch_bounds__(256) void k_prep(
    const float* __restrict__ W1, const float* __restrict__ W2, const float* __restrict__ Wf,
    const float* __restrict__ as1, const float* __restrict__ ad1,
    const float* __restrict__ as2, const float* __restrict__ ad2,
    unsigned short* __restrict__ Wst1, unsigned short* __restrict__ Wst2,
    unsigned short* __restrict__ Wft,
    float* __restrict__ av1, float* __restrict__ av2,
    int* __restrict__ deg, int* __restrict__ cursor,
    float* __restrict__ stats1, float* __restrict__ stats2)
{
  int b = blockIdx.x, t = threadIdx.x;
  if (b < PB_W1) {                                   // Wst1[c][h*FIN+k] = W1[k][h*C+c]
    int idx = b * 256 + t;
    int c = idx / (4 * FIN), r = idx - c * (4 * FIN);
    int h = r / FIN, k = r - h * FIN;
    Wst1[idx] = f2b(W1[(size_t)k * HC + h * C + c]);
    return;
  }
  b -= PB_W1;
  if (b < PB_W2) {                                   // Wst2[c][h*C+k] = W2[k][h*C+c]
    int idx = b * 256 + t;
    int c = idx / (4 * C), r = idx - c * (4 * C);
    int h = r / C, k = r - h * C;
    Wst2[idx] = f2b(W2[(size_t)k * HC + h * C + c]);
    return;
  }
  b -= PB_W2;
  if (b < PB_WF) {                                   // Wft[c][k] = Wf[k][c]
    int idx = b * 256 + t;
    int c = idx / C, k = idx - c * C;
    Wft[idx] = f2b(Wf[(size_t)k * C + c]);
    return;
  }
  b -= PB_WF;
  if (b < PB_AV1) {                                  // av1[j][k] = W1[k][hC:]·a_h
    int idx = b * 256 + t;
    int j = idx / FIN, k = idx - j * FIN, h = j & 3;
    const float* a = (j < 4) ? as1 : ad1;
    float s = 0.f;
    for (int c = 0; c < C; ++c) s += W1[(size_t)k * HC + h * C + c] * a[h * C + c];
    av1[idx] = s;
    return;
  }
  b -= PB_AV1;
  if (b < PB_AV2) {
    int idx = b * 256 + t;
    int j = idx / C, k = idx - j * C, h = j & 3;
    const float* a = (j < 4) ? as2 : ad2;
    float s = 0.f;
    for (int c = 0; c < C; ++c) s += W2[(size_t)k * HC + h * C + c] * a[h * C + c];
    av2[idx] = s;
    return;
  }
  b -= PB_AV2;
  {                                                  // zero deg, cursor, stats1, stats2
    int i = b * 256 + t;
    if (i < N) deg[i] = 0;
    else if (i < 2 * N) cursor[i - N] = 0;
    else {
      int i2 = i - 2 * N;
      if (i2 < 256) stats1[i2] = 0.f;
      else if (i2 < 512) stats2[i2 - 256] = 0.f;
    }
  }
}

// ------- layer-1: x(f32) -> xbf(bf16) + a_src/a_dst dots, one wave per node -------
__global__ __launch_bounds__(256) void k_attdots_cvt(
    const float* __restrict__ x, const float* __restrict__ av,
    unsigned short* __restrict__ xbf,
    float* __restrict__ asrc, float* __restrict__ adst)
{
  __shared__ float avs[8 * FIN];
  for (int i = threadIdx.x; i < 8 * FIN; i += 256) avs[i] = av[i];
  __syncthreads();
  int wid = threadIdx.x >> 6, lane = threadIdx.x & 63;
  int n = blockIdx.x * 4 + wid;
  f32x4 xv = __builtin_nontemporal_load(
      reinterpret_cast<const f32x4*>(x) + (size_t)n * (FIN / 4) + lane);
  u32x2 pk;
  pk.x = pack2(xv[0], xv[1]);
  pk.y = pack2(xv[2], xv[3]);
  *reinterpret_cast<u32x2*>(&xbf[(size_t)n * FIN + lane * 4]) = pk;
  float s[8];
#pragma unroll
  for (int j = 0; j < 8; ++j) {
    float t = 0.f;
#pragma unroll
    for (int q = 0; q < 4; ++q) t += xv[q] * avs[j * FIN + lane * 4 + q];
    s[j] = t;
  }
#pragma unroll
  for (int off = 1; off < 64; off <<= 1)
#pragma unroll
    for (int j = 0; j < 8; ++j) s[j] += __shfl_xor(s[j], off);
  if (lane == 0) {
    *reinterpret_cast<float4*>(&asrc[n * 4]) = make_float4(s[0], s[1], s[2], s[3]);
    *reinterpret_cast<float4*>(&adst[n * 4]) = make_float4(s[4], s[5], s[6], s[7]);
  }
}

// ---- layer-2 variant: fused BN(stats)+ReLU apply (xm -> xmb) + att dots ----
__global__ __launch_bounds__(256) void k_attdots_bn(
    const float* __restrict__ xm, const float* __restrict__ stats,
    const float* __restrict__ g, const float* __restrict__ be,
    const float* __restrict__ av, unsigned short* __restrict__ xmb,
    float* __restrict__ asrc, float* __restrict__ adst)
{
  __shared__ float avs[8 * C];
  __shared__ float bnsc[C], bnsh[C];
  int t = threadIdx.x;
  for (int i = t; i < 8 * C; i += 256) avs[i] = av[i];
  if (t < C) {
    float mu  = stats[t] * (1.f / N);
    float var = stats[C + t] * (1.f / N) - mu * mu;
    float sc  = rsqrtf(var + BN_EPS) * g[t];
    bnsc[t] = sc;
    bnsh[t] = be[t] - mu * sc;
  }
  __syncthreads();
  int wid = t >> 6, lane = t & 63;
  int n = blockIdx.x * 4 + wid;
  int c = lane * 2;
  float2 xv = *reinterpret_cast<const float2*>(&xm[(size_t)n * C + c]);
  float v0 = fmaxf(xv.x * bnsc[c]     + bnsh[c],     0.f);
  float v1 = fmaxf(xv.y * bnsc[c + 1] + bnsh[c + 1], 0.f);
  *reinterpret_cast<unsigned*>(&xmb[(size_t)n * C + c]) = pack2(v0, v1);
  float s[8];
#pragma unroll
  for (int j = 0; j < 8; ++j)
    s[j] = v0 * avs[j * C + c] + v1 * avs[j * C + c + 1];
#pragma unroll
  for (int off = 1; off < 64; off <<= 1)
#pragma unroll
    for (int j = 0; j < 8; ++j) s[j] += __shfl_xor(s[j], off);
  if (lane == 0) {
    *reinterpret_cast<float4*>(&asrc[n * 4]) = make_float4(s[0], s[1], s[2], s[3]);
    *reinterpret_cast<float4*>(&adst[n * 4]) = make_float4(s[4], s[5], s[6], s[7]);
  }
}

// ---------------- CSR build ----------------
__global__ void k_deg(const int* __restrict__ edst, int* __restrict__ deg) {
  int e = blockIdx.x * blockDim.x + threadIdx.x;
  if (e >= ETOT) return;
  int d = (e < E) ? edst[e] : (e - E);
  atomicAdd(&deg[d], 1);
}

__global__ __launch_bounds__(1024) void k_scan(const int* __restrict__ deg,
                                               int* __restrict__ offs) {
  __shared__ int sums[1024];
  int t = threadIdx.x;
  int base = t * 32;
  int local[32];
  int tot = 0;
#pragma unroll
  for (int i = 0; i < 32; ++i) { local[i] = deg[base + i]; tot += local[i]; }
  sums[t] = tot;
  __syncthreads();
  for (int off = 1; off < 1024; off <<= 1) {
    int v = (t >= off) ? sums[t - off] : 0;
    __syncthreads();
    sums[t] += v;
    __syncthreads();
  }
  int run = (t == 0) ? 0 : sums[t - 1];
#pragma unroll
  for (int i = 0; i < 32; ++i) { offs[base + i] = run; run += local[i]; }
  if (t == 1023) offs[N] = run;
}

__global__ void k_scatter(const int* __restrict__ esrc, const int* __restrict__ edst,
                          const int* __restrict__ offs, int* __restrict__ cursor,
                          int* __restrict__ csrc) {
  int e = blockIdx.x * blockDim.x + threadIdx.x;
  if (e >= ETOT) return;
  int s = (e < E) ? esrc[e] : (e - E);
  int d = (e < E) ? edst[e] : (e - E);
  int pos = offs[d] + atomicAdd(&cursor[d], 1);
  csrc[pos] = s;
}

// ---------------- edge exp + denom-inverse (max-free softmax), 16 lanes/node ----------
__global__ __launch_bounds__(256) void k_eexp(
    const int* __restrict__ offs, const int* __restrict__ csrc,
    const float* __restrict__ asrc, const float* __restrict__ adst,
    float* __restrict__ pbuf, float* __restrict__ denominv)
{
  int gid = blockIdx.x * 256 + threadIdx.x;
  int n = gid >> 4, l = gid & 15;
  int beg = offs[n], end = offs[n + 1];
  const float4 bv = *reinterpret_cast<const float4*>(&adst[n * 4]);
  float d0 = 0.f, d1 = 0.f, d2 = 0.f, d3 = 0.f;
  for (int i = beg + l; i < end; i += 16) {
    int s = csrc[i];
    float4 av = *reinterpret_cast<const float4*>(&asrc[s * 4]);
    float p0 = __expf(lrelu(av.x + bv.x));
    float p1 = __expf(lrelu(av.y + bv.y));
    float p2 = __expf(lrelu(av.z + bv.z));
    float p3 = __expf(lrelu(av.w + bv.w));
    *reinterpret_cast<float4*>(&pbuf[(size_t)i * 4]) = make_float4(p0, p1, p2, p3);
    d0 += p0; d1 += p1; d2 += p2; d3 += p3;
  }
#pragma unroll
  for (int off = 1; off < 16; off <<= 1) {
    d0 += __shfl_xor(d0, off);
    d1 += __shfl_xor(d1, off);
    d2 += __shfl_xor(d2, off);
    d3 += __shfl_xor(d3, off);
  }
  if (l == 0)
    *reinterpret_cast<float4*>(&denominv[n * 4]) =
        make_float4(0.25f / (d0 + 1e-16f), 0.25f / (d1 + 1e-16f),
                    0.25f / (d2 + 1e-16f), 0.25f / (d3 + 1e-16f));
}

// ---------------- aggregate-of-inputs (p precomputed, coalesced stage) ----------------
// one wave per node; z[n][h*DIN+k] = denominv_h * sum_e p_e,h * x[src_e][k]
// csrc/pbuf read nontemporal (read-once); z stored nontemporal (streamed);
// xb (the gathered rows, reused across nodes) kept cacheable.
template<int DIN>
__global__ __launch_bounds__(256) void k_fused_agg(
    const unsigned short* __restrict__ xb, const int* __restrict__ offs,
    const int* __restrict__ csrc, const float* __restrict__ pbuf,
    const float* __restrict__ denominv, unsigned short* __restrict__ z)
{
  constexpr int CPL = DIN / 64;
  __shared__ float pls[4][64][4];
  __shared__ int   sls[4][64];
  const int wid = threadIdx.x >> 6, lane = threadIdx.x & 63;
  const int n = blockIdx.x * 4 + wid;
  const int beg = offs[n], end = offs[n + 1];

  float acc[4][CPL] = {};
  for (int base = beg; base < end; base += 64) {
    int i = base + lane;                 // csrc/pbuf over-allocated: no guard
    int s = __builtin_nontemporal_load(&csrc[i]);
    f32x4 pv = __builtin_nontemporal_load(reinterpret_cast<const f32x4*>(pbuf) + i);
    sls[wid][lane] = s;
    *reinterpret_cast<f32x4*>(&pls[wid][lane][0]) = pv;
    int cnt = end - base; if (cnt > 64) cnt = 64;
#pragma unroll 4
    for (int j = 0; j < cnt; ++j) {
      int sj = sls[wid][j];
      f32x4 pj = *reinterpret_cast<const f32x4*>(&pls[wid][j][0]);
      if constexpr (CPL == 4) {
        uint2 u = *reinterpret_cast<const uint2*>(&xb[(size_t)sj * DIN + lane * 4]);
        float c0 = blo(u.x), c1 = bhi(u.x), c2 = blo(u.y), c3 = bhi(u.y);
        acc[0][0] += pj[0] * c0; acc[0][1] += pj[0] * c1; acc[0][2] += pj[0] * c2; acc[0][3] += pj[0] * c3;
        acc[1][0] += pj[1] * c0; acc[1][1] += pj[1] * c1; acc[1][2] += pj[1] * c2; acc[1][3] += pj[1] * c3;
        acc[2][0] += pj[2] * c0; acc[2][1] += pj[2] * c1; acc[2][2] += pj[2] * c2; acc[2][3] += pj[2] * c3;
        acc[3][0] += pj[3] * c0; acc[3][1] += pj[3] * c1; acc[3][2] += pj[3] * c2; acc[3][3] += pj[3] * c3;
      } else {
        unsigned u = *reinterpret_cast<const unsigned*>(&xb[(size_t)sj * DIN + lane * 2]);
        float c0 = blo(u), c1 = bhi(u);
        acc[0][0] += pj[0] * c0; acc[0][1] += pj[0] * c1;
        acc[1][0] += pj[1] * c0; acc[1][1] += pj[1] * c1;
        acc[2][0] += pj[2] * c0; acc[2][1] += pj[2] * c1;
        acc[3][0] += pj[3] * c0; acc[3][1] += pj[3] * c1;
      }
    }
  }
  const float4 iv4 = *reinterpret_cast<const float4*>(&denominv[n * 4]);
  const float inv[4] = { iv4.x, iv4.y, iv4.z, iv4.w };
  size_t zb = (size_t)n * 4 * DIN;
#pragma unroll
  for (int h = 0; h < 4; ++h) {
    if constexpr (CPL == 4) {
      u32x2 o;
      o.x = pack2(acc[h][0] * inv[h], acc[h][1] * inv[h]);
      o.y = pack2(acc[h][2] * inv[h], acc[h][3] * inv[h]);
      __builtin_nontemporal_store(
          o, reinterpret_cast<u32x2*>(&z[zb + h * DIN + lane * 4]));
    } else {
      __builtin_nontemporal_store(
          pack2(acc[h][0] * inv[h], acc[h][1] * inv[h]),
          reinterpret_cast<unsigned*>(&z[zb + h * DIN + lane * 2]));
    }
  }
}

// ---------------- MFMA bf16 GEMM: O[M,128] f32 = A[M,K] @ Bt[128,K]^T (+bias) ----
__global__ __launch_bounds__(256) void gemm_bt(
    const unsigned short* __restrict__ A,
    const unsigned short* __restrict__ Bt,
    const float* __restrict__ bias,
    float* __restrict__ O, int K)
{
  __shared__ unsigned short As[64 * 32];
  __shared__ unsigned short Bs[128 * 32];
  const int tid  = threadIdx.x;
  const int wave = tid >> 6, lane = tid & 63;
  const int wr = (wave >> 1) * 32, wc = (wave & 1) * 64;
  const int row0 = blockIdx.x * 64;

  const int fr = lane & 15, kqc = lane >> 4;
  const int sl_r = lane >> 2;
  const int sl_c = lane & 3;

  const int ra  = (wave << 4) + sl_r;
  const int ca  = (sl_c ^ ((ra >> 1) & 3)) * 8;
  const int rb0 = (wave << 5) + sl_r;
  const int cb0 = (sl_c ^ ((rb0 >> 1) & 3)) * 8;
  const int rb1 = rb0 + 16;
  const int cb1 = (sl_c ^ ((rb1 >> 1) & 3)) * 8;

  f32x4 acc[2][4] = {};
  for (int k0 = 0; k0 < K; k0 += 32) {
    gll16(&A [(size_t)(row0 + ra) * K + k0 + ca ], &As[(size_t)(wave << 4) * 32]);
    gll16(&Bt[(size_t)rb0         * K + k0 + cb0], &Bs[(size_t)(wave << 5) * 32]);
    gll16(&Bt[(size_t)rb1         * K + k0 + cb1], &Bs[(size_t)((wave << 5) + 16) * 32]);
    __syncthreads();

    bf16x8 af[2], bfr[4];
#pragma unroll
    for (int m = 0; m < 2; ++m) {
      int r = wr + m * 16 + fr;
      af[m] = *(const bf16x8*)&As[r * 32 + (kqc ^ ((r >> 1) & 3)) * 8];
    }
#pragma unroll
    for (int nn = 0; nn < 4; ++nn) {
      int r = wc + nn * 16 + fr;
      bfr[nn] = *(const bf16x8*)&Bs[r * 32 + (kqc ^ ((r >> 1) & 3)) * 8];
    }
#pragma unroll
    for (int m = 0; m < 2; ++m)
#pragma unroll
      for (int nn = 0; nn < 4; ++nn)
        acc[m][nn] = __builtin_amdgcn_mfma_f32_16x16x32_bf16(af[m], bfr[nn], acc[m][nn], 0, 0, 0);
    __syncthreads();
  }

  const int fq = (lane >> 4) * 4;
#pragma unroll
  for (int m = 0; m < 2; ++m)
#pragma unroll
    for (int nn = 0; nn < 4; ++nn) {
      int col = wc + nn * 16 + fr;
      float bv = bias ? bias[col] : 0.f;
#pragma unroll
      for (int j = 0; j < 4; ++j) {
        int row = row0 + wr + m * 16 + fq + j;
        O[(size_t)row * 128 + col] = acc[m][nn][j] + bv;
      }
    }
}

// ---------------- BN stats (sum, sumsq per channel) ----------------
__global__ __launch_bounds__(128) void k_bn_stats(const float* __restrict__ x,
                                                  float* __restrict__ stats) {
  int c = threadIdx.x;
  int rows = N / gridDim.x;
  int r0 = blockIdx.x * rows;
  float s = 0.f, s2 = 0.f;
  for (int r = r0; r < r0 + rows; ++r) {
    float v = x[(size_t)r * C + c];
    s += v; s2 += v * v;
  }
  atomicAdd(&stats[c], s);
  atomicAdd(&stats[C + c], s2);
}

// ---------------- BN apply + ReLU -> bf16 ----------------
__global__ void k_bn_apply(const float* __restrict__ stats, const float* __restrict__ g,
                           const float* __restrict__ be, const float* __restrict__ xin,
                           unsigned short* __restrict__ xb) {
  int i = blockIdx.x * blockDim.x + threadIdx.x;
  if (i >= N * C) return;
  int c = i & (C - 1);
  float mu  = stats[c] * (1.f / N);
  float var = stats[C + c] * (1.f / N) - mu * mu;
  float v = (xin[i] - mu) * rsqrtf(var + BN_EPS) * g[c] + be[c];
  xb[i] = f2b(v > 0.f ? v : 0.f);
}

} // namespace

extern "C" void kernel_launch(void* const* d_in, const int* in_sizes, int n_in,
                              void* d_out, int out_size, void* d_ws, size_t ws_size,
                              hipStream_t stream) {
  const float* x   = (const float*)d_in[0];
  const int*   ei  = (const int*)d_in[1];
  const float* W1  = (const float*)d_in[2];
  const float* as1 = (const float*)d_in[3];
  const float* ad1 = (const float*)d_in[4];
  const float* g1  = (const float*)d_in[6];
  const float* be1 = (const float*)d_in[7];
  const float* W2  = (const float*)d_in[8];
  const float* as2 = (const float*)d_in[9];
  const float* ad2 = (const float*)d_in[10];
  const float* g2  = (const float*)d_in[12];
  const float* be2 = (const float*)d_in[13];
  const float* Wf  = (const float*)d_in[14];
  const float* bf  = (const float*)d_in[15];
  float* out = (float*)d_out;
  // b1/b2 (d_in[5], d_in[11]) skipped: BN output is invariant to a
  // per-channel constant shift before it.

  const int* esrc = ei;
  const int* edst = ei + E;

  // ---- workspace layout ----
  char* p = (char*)d_ws;
  auto alloc = [&](size_t bytes) {
    char* r = p;
    p += (bytes + 255) & ~size_t(255);
    return r;
  };
  unsigned short* z1   = (unsigned short*)alloc(2ull * N * 4 * FIN);  // 64 MB (layer2 reuses)
  unsigned short* xbf  = (unsigned short*)alloc(2ull * N * FIN);      // 16 MB
  unsigned short* xmb  = (unsigned short*)alloc(2ull * N * C);        // 8 MB
  float*    xm     = (float*)alloc(sizeof(float) * (size_t)N * C);    // 16 MB
  float*    pbuf   = (float*)alloc(sizeof(float) * (size_t)(ETOT + 64) * 4); // 8.9 MB
  unsigned short* Wst1 = (unsigned short*)alloc(2ull * C * 4 * FIN);
  unsigned short* Wst2 = (unsigned short*)alloc(2ull * C * 4 * C);
  unsigned short* Wft  = (unsigned short*)alloc(2ull * C * C);
  float*    av1    = (float*)alloc(sizeof(float) * 8 * FIN);
  float*    av2    = (float*)alloc(sizeof(float) * 8 * C);
  float*    asrc   = (float*)alloc(sizeof(float) * N * 4);
  float*    adst   = (float*)alloc(sizeof(float) * N * 4);
  float*    denominv = (float*)alloc(sizeof(float) * N * 4);
  float*    stats1 = (float*)alloc(sizeof(float) * 2 * C);
  float*    stats2 = (float*)alloc(sizeof(float) * 2 * C);
  int*      deg    = (int*)alloc(sizeof(int) * N);
  int*      offs   = (int*)alloc(sizeof(int) * (N + 16));
  int*      cursor = (int*)alloc(sizeof(int) * N);
  int*      csrc   = (int*)alloc(sizeof(int) * (ETOT + 64));
  (void)ws_size; (void)in_sizes; (void)n_in; (void)out_size;

  const int EB = (ETOT + 255) / 256;

  // ---- prep: weight converts + attvecs + zeroing ----
  k_prep<<<PB_TOT, 256, 0, stream>>>(W1, W2, Wf, as1, ad1, as2, ad2,
                                     Wst1, Wst2, Wft, av1, av2,
                                     deg, cursor, stats1, stats2);

  // ---- CSR build ----
  k_deg<<<EB, 256, 0, stream>>>(edst, deg);
  k_scan<<<1, 1024, 0, stream>>>(deg, offs);
  k_scatter<<<EB, 256, 0, stream>>>(esrc, edst, offs, cursor, csrc);

  // ---- layer 1 (x convert fused into dots) ----
  k_attdots_cvt<<<N / 4, 256, 0, stream>>>(x, av1, xbf, asrc, adst);
  k_eexp<<<(N * 16) / 256, 256, 0, stream>>>(offs, csrc, asrc, adst, pbuf, denominv);
  k_fused_agg<FIN><<<N / 4, 256, 0, stream>>>(xbf, offs, csrc, pbuf, denominv, z1);
  gemm_bt<<<N / 64, 256, 0, stream>>>(z1, Wst1, nullptr, xm, 4 * FIN);
  k_bn_stats<<<256, C, 0, stream>>>(xm, stats1);

  // ---- layer 2 (BN1 apply fused into attdots) ----
  k_attdots_bn<<<N / 4, 256, 0, stream>>>(xm, stats1, g1, be1, av2, xmb, asrc, adst);
  k_eexp<<<(N * 16) / 256, 256, 0, stream>>>(offs, csrc, asrc, adst, pbuf, denominv);
  k_fused_agg<C><<<N / 4, 256, 0, stream>>>(xmb, offs, csrc, pbuf, denominv, z1);
  gemm_bt<<<N / 64, 256, 0, stream>>>(z1, Wst2, nullptr, xm, 4 * C);
  k_bn_stats<<<256, C, 0, stream>>>(xm, stats2);
  k_bn_apply<<<(N * C) / 256, 256, 0, stream>>>(stats2, g2, be2, xm, xmb);

  // ---- final linear (f32 out + bias) ----
  gemm_bt<<<N / 64, 256, 0, stream>>>(xmb, Wft, bf, out, C);
}